// Round 1
// baseline (307034.375 us; speedup 1.0000x reference)
//
#include <hip/hip_runtime.h>
#include <math.h>

// ============================================================
// Tacotron2 decoder, fp32 reference-faithful implementation.
// B=64, T_ENC=512, T_DEC=500, MEL=80, PRE=256, ENC_D=512, H=1024, ATT=128
//
// Round-1 goals: correctness + clean structure + profile data.
//  - prolog (parallel): weight transposes, fused location kernel,
//    prenet for all 500 steps (teacher forcing), mem = enc@am.T
//  - 500 sequential steps x 5 kernels:
//      k_energy -> k_softmax_ctx -> k_gates_cell(L0) -> k_gates_cell(L1) -> k_melstop_q
//  - epilog (parallel): 5-layer conv postnet
// h0/h1 double-buffered by step parity (avoids intra-kernel cross-block races).
// ============================================================

// ---------------- ws layout (float offsets) ----------------
static constexpr long OFF_AMT  = 0;                       // amT[512][128]
static constexpr long OFF_P1WT = OFF_AMT  + 512L*128;     // p1wT[80][256]
static constexpr long OFF_P2WT = OFF_P1WT + 80L*256;      // p2wT[256][256]
static constexpr long OFF_MWT  = OFF_P2WT + 256L*256;     // mwT[1536][80]
static constexpr long OFF_AQT  = OFF_MWT  + 1536L*80;     // aqT[1024][128]
static constexpr long OFF_WLOC = OFF_AQT  + 1024L*128;    // W_loc[128][32] (31 used)
static constexpr long OFF_BLOC = OFF_WLOC + 128L*32;      // bloc[128] = al@alcb + ab
static constexpr long OFF_GB0  = OFF_BLOC + 128;          // bih0+bhh0 [4096]
static constexpr long OFF_GB1  = OFF_GB0  + 4096;         // bih1+bhh1 [4096]
static constexpr long OFF_PWT0 = OFF_GB1  + 4096;         // postnet wT0 [400][512]
static constexpr long OFF_PWT1 = OFF_PWT0 + 400L*512;     // [2560][512]
static constexpr long OFF_PWT2 = OFF_PWT1 + 2560L*512;
static constexpr long OFF_PWT3 = OFF_PWT2 + 2560L*512;
static constexpr long OFF_PWT4 = OFF_PWT3 + 2560L*512;    // [2560][80]
static constexpr long OFF_PRE  = OFF_PWT4 + 2560L*80;     // pre_all[500*64][256]
static constexpr long OFF_MEM  = OFF_PRE  + 500L*64*256;  // mem[64][512][128]
static constexpr long OFF_H0A  = OFF_MEM  + 64L*512*128;  // -- zero region start --
static constexpr long OFF_H0B  = OFF_H0A  + 64L*1024;
static constexpr long OFF_H1A  = OFF_H0B  + 64L*1024;
static constexpr long OFF_H1B  = OFF_H1A  + 64L*1024;
static constexpr long OFF_C0   = OFF_H1B  + 64L*1024;
static constexpr long OFF_C1   = OFF_C0   + 64L*1024;
static constexpr long OFF_Q    = OFF_C1   + 64L*1024;     // q[64][128]
static constexpr long OFF_CTX  = OFF_Q    + 64L*128;      // ctx[64][512]
static constexpr long OFF_EBUF = OFF_CTX  + 64L*512;      // e[64][512]
static constexpr long OFF_PB0  = OFF_EBUF + 64L*512;      // postnet buf [64][512][500]
static constexpr long OFF_PB1  = OFF_PB0  + 64L*512*500;
static constexpr long WS_FLOATS = OFF_PB1 + 64L*512*500;  // ~201.5 MB

// d_out layout: [mel+post | mel | stop | attw]
static constexpr long DO_MEL  = 64L*500*80;      // 2,560,000
static constexpr long DO_STOP = 2*DO_MEL;        // 5,120,000
static constexpr long DO_ATT  = DO_STOP + 64L*500; // 5,152,000

static constexpr long ZERO_CNT = OFF_EBUF - OFF_H0A;  // h/c x6 + q + ctx = 434176
static constexpr long PREP_TOTAL = ZERO_CNT + 4096 + 4096 + 4096 + 128
  + 65536 + 20480 + 65536 + 122880 + 131072
  + 204800 + 1310720 + 1310720 + 1310720 + 204800;   // 5,193,856

__device__ __forceinline__ float fsigmoid(float x) { return 1.f / (1.f + __expf(-x)); }
__device__ __forceinline__ float ftanh(float x) {
  float ax = fminf(fabsf(x), 15.f);
  float e = __expf(-2.f * ax);
  float r = (1.f - e) / (1.f + e);
  return copysignf(r, x);
}

// ---------------- prolog: transposes / fused constants / zero-init ----------------
__global__ __launch_bounds__(256) void k_prep(
    const float* __restrict__ bih0, const float* __restrict__ bhh0,
    const float* __restrict__ bih1, const float* __restrict__ bhh1,
    const float* __restrict__ al,   const float* __restrict__ alcw,
    const float* __restrict__ alcb, const float* __restrict__ ab,
    const float* __restrict__ am,   const float* __restrict__ p1w,
    const float* __restrict__ p2w,  const float* __restrict__ mw,
    const float* __restrict__ aq,
    const float* __restrict__ pw0, const float* __restrict__ pw1,
    const float* __restrict__ pw2, const float* __restrict__ pw3,
    const float* __restrict__ pw4,
    float* __restrict__ ws)
{
  long stride = (long)gridDim.x * 256;
  for (long idx = (long)blockIdx.x * 256 + threadIdx.x; idx < PREP_TOTAL; idx += stride) {
    long r = idx;
    if (r < ZERO_CNT) { ws[OFF_H0A + r] = 0.f; continue; }
    r -= ZERO_CNT;
    if (r < 4096) { ws[OFF_GB0 + r] = bih0[r] + bhh0[r]; continue; }
    r -= 4096;
    if (r < 4096) { ws[OFF_GB1 + r] = bih1[r] + bhh1[r]; continue; }
    r -= 4096;
    if (r < 4096) {   // fused location kernel W_loc[a][k] = sum_c al[a,c]*alcw[c,0,k]
      int a = (int)(r >> 5), k = (int)(r & 31);
      float v = 0.f;
      if (k < 31) for (int ch = 0; ch < 32; ++ch) v += al[a*32 + ch] * alcw[ch*31 + k];
      ws[OFF_WLOC + r] = v; continue;
    }
    r -= 4096;
    if (r < 128) {    // bloc[a] = sum_c al[a,c]*alcb[c] + ab[a]
      float v = ab[r];
      for (int ch = 0; ch < 32; ++ch) v += al[r*32 + ch] * alcb[ch];
      ws[OFF_BLOC + r] = v; continue;
    }
    r -= 128;
    if (r < 65536) { int d = (int)(r >> 7), a2 = (int)(r & 127); ws[OFF_AMT + r] = am[(long)a2*512 + d]; continue; }
    r -= 65536;
    if (r < 20480) { int k = (int)(r >> 8), j = (int)(r & 255); ws[OFF_P1WT + r] = p1w[j*80 + k]; continue; }
    r -= 20480;
    if (r < 65536) { int k = (int)(r >> 8), j = (int)(r & 255); ws[OFF_P2WT + r] = p2w[j*256 + k]; continue; }
    r -= 65536;
    if (r < 122880) { int k = (int)(r / 80), c = (int)(r % 80); ws[OFF_MWT + r] = mw[(long)c*1536 + k]; continue; }
    r -= 122880;
    if (r < 131072) { int k = (int)(r >> 7), a2 = (int)(r & 127); ws[OFF_AQT + r] = aq[(long)a2*1024 + k]; continue; }
    r -= 131072;
    if (r < 204800) { int c5 = (int)(r / 512), co = (int)(r % 512); ws[OFF_PWT0 + r] = pw0[((long)co*80  + c5/5)*5 + (c5%5)]; continue; }
    r -= 204800;
    if (r < 1310720) { int c5 = (int)(r / 512), co = (int)(r % 512); ws[OFF_PWT1 + r] = pw1[((long)co*512 + c5/5)*5 + (c5%5)]; continue; }
    r -= 1310720;
    if (r < 1310720) { int c5 = (int)(r / 512), co = (int)(r % 512); ws[OFF_PWT2 + r] = pw2[((long)co*512 + c5/5)*5 + (c5%5)]; continue; }
    r -= 1310720;
    if (r < 1310720) { int c5 = (int)(r / 512), co = (int)(r % 512); ws[OFF_PWT3 + r] = pw3[((long)co*512 + c5/5)*5 + (c5%5)]; continue; }
    r -= 1310720;
    { int c5 = (int)(r / 80), co = (int)(r % 80); ws[OFF_PWT4 + r] = pw4[((long)co*512 + c5/5)*5 + (c5%5)]; }
  }
}

// ---------------- prolog: prenet for all 500 steps (teacher forcing) ----------------
__global__ __launch_bounds__(256) void k_prenet(
    const float* __restrict__ mel_tgt, const float* __restrict__ p1b,
    const float* __restrict__ p2b, float* __restrict__ ws)
{
  int t = blockIdx.x, tid = threadIdx.x;
  const float* p1wT = ws + OFF_P1WT;
  const float* p2wT = ws + OFF_P2WT;
  __shared__ float prev_s[16][80];
  __shared__ float h1_s[16][256];
  for (int sb = 0; sb < 4; ++sb) {
    int b0 = sb * 16;
    for (int i = tid; i < 16*80; i += 256) {
      int rr = i / 80, k = i - rr*80;
      float v = 0.f;
      if (t > 0) v = mel_tgt[((long)(b0 + rr)*500 + (t-1))*80 + k];
      prev_s[rr][k] = v;
    }
    __syncthreads();
    int j = tid;
    for (int rr = 0; rr < 16; ++rr) {
      float acc = p1b[j];
      for (int k = 0; k < 80; ++k) acc = fmaf(prev_s[rr][k], p1wT[k*256 + j], acc);
      h1_s[rr][j] = fmaxf(acc, 0.f);
    }
    __syncthreads();
    for (int rr = 0; rr < 16; ++rr) {
      float acc = p2b[j];
      for (int k = 0; k < 256; ++k) acc = fmaf(h1_s[rr][k], p2wT[k*256 + j], acc);
      ws[OFF_PRE + ((long)t*64 + b0 + rr)*256 + j] = fmaxf(acc, 0.f);
    }
    __syncthreads();
  }
}

// ---------------- prolog: mem = enc @ am.T  [64*512 rows][128] ----------------
__global__ __launch_bounds__(256) void k_mem(const float* __restrict__ enc, float* __restrict__ ws)
{
  int row0 = blockIdx.x * 16;
  int tid = threadIdx.x;
  int a = tid & 127, rh = tid >> 7;
  const float* amT = ws + OFF_AMT;
  __shared__ float encS[16][65];
  float acc[8];
#pragma unroll
  for (int i = 0; i < 8; ++i) acc[i] = 0.f;
  for (int k0 = 0; k0 < 512; k0 += 64) {
    for (int i = tid; i < 16*64; i += 256) {
      int rr = i >> 6, kk = i & 63;
      encS[rr][kk] = enc[(long)(row0 + rr)*512 + k0 + kk];
    }
    __syncthreads();
    for (int kk = 0; kk < 64; ++kk) {
      float w = amT[(long)(k0 + kk)*128 + a];
#pragma unroll
      for (int rr = 0; rr < 8; ++rr) acc[rr] = fmaf(encS[rh*8 + rr][kk], w, acc[rr]);
    }
    __syncthreads();
  }
#pragma unroll
  for (int rr = 0; rr < 8; ++rr)
    ws[OFF_MEM + (long)(row0 + rh*8 + rr)*128 + a] = acc[rr];
}

// ---------------- per-step: attention energies ----------------
// grid (8, 64): block (te-chunk of 64, b); thread: te_l = tid&63, a-quarter = tid>>6
__global__ __launch_bounds__(256) void k_energy(
    const float* __restrict__ ae, const float* __restrict__ dout,
    float* __restrict__ ws, int t)
{
  int c = blockIdx.x, b = blockIdx.y, tid = threadIdx.x;
  int te_l = tid & 63, qa = tid >> 6;
  __shared__ float Wl[4096];
  __shared__ float bq[128], ae_s[128];
  __shared__ float ap[94];
  __shared__ float epart[4][64];
  for (int i = tid; i < 4096; i += 256) Wl[i] = ws[OFF_WLOC + i];
  if (tid < 128) {
    bq[tid] = ws[OFF_Q + b*128 + tid] + ws[OFF_BLOC + tid];
    ae_s[tid] = ae[tid];
  }
  for (int i = tid; i < 94; i += 256) {
    int gte = c*64 + i - 15;
    float v = 0.f;
    if (t > 0 && gte >= 0 && gte < 512)
      v = dout[DO_ATT + ((long)b*500 + (t-1))*512 + gte];
    ap[i] = v;
  }
  __syncthreads();
  int te_g = c*64 + te_l;
  const float* memp = ws + OFF_MEM + ((long)b*512 + te_g)*128;
  float e = 0.f;
  int a0 = qa * 32;
  for (int a = a0; a < a0 + 32; ++a) {
    float acc = bq[a] + memp[a];
#pragma unroll
    for (int k = 0; k < 31; ++k) acc = fmaf(ap[te_l + k], Wl[a*32 + k], acc);
    e = fmaf(ae_s[a], ftanh(acc), e);
  }
  epart[qa][te_l] = e;
  __syncthreads();
  if (tid < 64)
    ws[OFF_EBUF + (long)b*512 + c*64 + tid] =
        epart[0][tid] + epart[1][tid] + epart[2][tid] + epart[3][tid];
}

// ---------------- per-step: softmax + ctx (deterministic, no atomics) ----------------
// grid (4, 64): each block redoes softmax (cheap) and owns a 128-wide d-slice of ctx.
__global__ __launch_bounds__(256) void k_softmax_ctx(
    const float* __restrict__ enc, float* __restrict__ dout,
    float* __restrict__ ws, int t)
{
  int c = blockIdx.x, b = blockIdx.y, tid = threadIdx.x;
  __shared__ float es[512];
  __shared__ float red[256];
  const float* eb = ws + OFF_EBUF + (long)b*512;
  es[tid] = eb[tid]; es[tid + 256] = eb[tid + 256];
  __syncthreads();
  red[tid] = fmaxf(es[tid], es[tid + 256]);
  __syncthreads();
  for (int s = 128; s > 0; s >>= 1) {
    if (tid < s) red[tid] = fmaxf(red[tid], red[tid + s]);
    __syncthreads();
  }
  float mx = red[0];
  __syncthreads();
  float p0 = __expf(es[tid] - mx), p1 = __expf(es[tid + 256] - mx);
  es[tid] = p0; es[tid + 256] = p1;
  red[tid] = p0 + p1;
  __syncthreads();
  for (int s = 128; s > 0; s >>= 1) {
    if (tid < s) red[tid] += red[tid + s];
    __syncthreads();
  }
  float inv = 1.f / red[0];
  __syncthreads();
  es[tid] *= inv; es[tid + 256] *= inv;
  __syncthreads();
  if (tid < 128)
    dout[DO_ATT + ((long)b*500 + t)*512 + c*128 + tid] = es[c*128 + tid];
  // ctx over owned d-slice; te split over two thread halves
  int dl = tid & 127, th = tid >> 7;
  int d = c*128 + dl;
  const float* ep = enc + (long)b*512*512;
  float acc = 0.f;
#pragma unroll 4
  for (int te = th*256; te < th*256 + 256; ++te)
    acc = fmaf(es[te], ep[(long)te*512 + d], acc);
  red[tid] = acc;
  __syncthreads();
  if (tid < 128)
    ws[OFF_CTX + (long)b*512 + c*128 + tid] = red[tid] + red[tid + 128];
}

// ---------------- per-step: gate GEMM + fused LSTM cell ----------------
// grid 256: block jt owns units [jt*4, jt*4+4) across all 4 gates (16 weight rows).
// Threads: b = tid&63 (lane), g = tid>>6 (gate, wave-uniform -> scalar weight loads).
// mode 0: x = [pre(256)|ctx(512)|h0_prev(1024)], W = [wih0|whh0], K=1792
// mode 1: x = [h0_new(1024)|h1_prev(1024)],      W = [wih1|whh1], K=2048
__global__ __launch_bounds__(256) void k_gates_cell(
    const float* __restrict__ wih, const float* __restrict__ whh,
    const float* __restrict__ gb, float* __restrict__ ws,
    int mode, int t, int p)
{
  int jt = blockIdx.x;
  int tid = threadIdx.x;
  int b = tid & 63;
  int g = __builtin_amdgcn_readfirstlane((int)(tid >> 6));
  int u0 = jt * 4;
  const int K  = mode ? 2048 : 1792;
  const int KH = mode ? 1024 : 768;   // wih/whh boundary in k
  const int LD = mode ? 1024 : 768;   // wih row length
  __shared__ float xs[64][65];
  __shared__ float gsh[4][64][4];
  float acc0 = gb[g*1024 + u0 + 0];
  float acc1 = gb[g*1024 + u0 + 1];
  float acc2 = gb[g*1024 + u0 + 2];
  float acc3 = gb[g*1024 + u0 + 3];
  const float* srcPre = ws + OFF_PRE + (long)t*64*256;
  const float* srcCtx = ws + OFF_CTX;
  const float* h0r = ws + OFF_H0A + (long)p*65536;        // prev h0
  const float* h0n = ws + OFF_H0A + (long)(1 - p)*65536;  // new h0 (mode1 input)
  const float* h1r = ws + OFF_H1A + (long)p*65536;        // prev h1
  for (int k0 = 0; k0 < K; k0 += 64) {
#pragma unroll
    for (int i = 0; i < 16; ++i) {
      int flat = tid + i*256;
      int bb = flat >> 6, kk = flat & 63;
      int k = k0 + kk;
      float v;
      if (mode == 0) {
        if (k < 256)      v = srcPre[bb*256 + k];
        else if (k < 768) v = srcCtx[bb*512 + (k - 256)];
        else              v = h0r[bb*1024 + (k - 768)];
      } else {
        if (k < 1024)     v = h0n[bb*1024 + k];
        else              v = h1r[bb*1024 + (k - 1024)];
      }
      xs[bb][kk] = v;
    }
    __syncthreads();
    long jbase = (long)g*1024 + u0;
    const float* r0;
    long ld;
    if (k0 < KH) { r0 = wih + jbase*LD + k0; ld = LD; }
    else         { r0 = whh + jbase*1024 + (k0 - KH); ld = 1024; }
    const float* r1 = r0 + ld;
    const float* r2 = r1 + ld;
    const float* r3 = r2 + ld;
#pragma unroll 16
    for (int kk = 0; kk < 64; ++kk) {
      float xv = xs[b][kk];
      acc0 = fmaf(xv, r0[kk], acc0);
      acc1 = fmaf(xv, r1[kk], acc1);
      acc2 = fmaf(xv, r2[kk], acc2);
      acc3 = fmaf(xv, r3[kk], acc3);
    }
    __syncthreads();
  }
  gsh[g][b][0] = acc0; gsh[g][b][1] = acc1; gsh[g][b][2] = acc2; gsh[g][b][3] = acc3;
  __syncthreads();
  {
    int u4 = g;   // each gate-group applies the cell for one of the 4 units
    float iv = gsh[0][b][u4];
    float fv = gsh[1][b][u4];
    float gv = gsh[2][b][u4];
    float ov = gsh[3][b][u4];
    long hw = (mode ? OFF_H1A : OFF_H0A) + (long)(1 - p)*65536 + (long)b*1024 + u0 + u4;
    long cw = (mode ? OFF_C1 : OFF_C0) + (long)b*1024 + u0 + u4;
    float cold = ws[cw];
    float c2 = fsigmoid(fv)*cold + fsigmoid(iv)*ftanh(gv);
    ws[cw] = c2;
    ws[hw] = fsigmoid(ov)*ftanh(c2);
  }
}

// ---------------- per-step: mel/stop heads + q for next step ----------------
__global__ __launch_bounds__(256) void k_melstop_q(
    const float* __restrict__ mb, const float* __restrict__ sw, const float* __restrict__ sb,
    float* __restrict__ dout, float* __restrict__ ws, int t, int p)
{
  int b = blockIdx.x, tid = threadIdx.x;
  __shared__ float xs[1536];
  const float* h1n = ws + OFF_H1A + (long)(1 - p)*65536;  // new h1
  const float* ctx = ws + OFF_CTX;
  for (int i = tid; i < 1536; i += 256)
    xs[i] = (i < 1024) ? h1n[b*1024 + i] : ctx[b*512 + (i - 1024)];
  __syncthreads();
  const float* mwT = ws + OFF_MWT;
  const float* aqT = ws + OFF_AQT;
  if (tid < 80) {
    float acc = mb[tid];
    for (int k = 0; k < 1536; ++k) acc = fmaf(xs[k], mwT[k*80 + tid], acc);
    dout[DO_MEL + ((long)b*500 + t)*80 + tid] = acc;
  } else if (tid == 80) {
    float acc = sb[0];
    for (int k = 0; k < 1536; ++k) acc = fmaf(xs[k], sw[k], acc);
    dout[DO_STOP + (long)b*500 + t] = acc;
  } else if (tid >= 128) {
    int a = tid - 128;
    float acc = 0.f;
    for (int k = 0; k < 1024; ++k) acc = fmaf(xs[k], aqT[k*128 + a], acc);
    ws[OFF_Q + b*128 + a] = acc;   // q for step t+1
  }
}

// ---------------- epilog: postnet conv layer ----------------
// flags: bit0 = input is mel [b][t][80]; bit1 = output is mel+post [b][t][80]; bit2 = tanh
__global__ __launch_bounds__(256) void k_conv(
    const float* __restrict__ in, float* __restrict__ out,
    const float* __restrict__ wT, const float* __restrict__ pb,
    const float* __restrict__ bg, const float* __restrict__ bbp,
    const float* __restrict__ melp,
    int CI, int CO, int flags)
{
  int tx = blockIdx.x, cy = blockIdx.y, b = blockIdx.z;
  int tid = threadIdx.x;
  int tl = tid & 63;
  int cog = __builtin_amdgcn_readfirstlane((int)(tid >> 6));
  int t0 = tx * 64;
  int co0 = cy*64 + cog*16;
  __shared__ float xs[16][68];
  float acc[16];
#pragma unroll
  for (int i = 0; i < 16; ++i) acc[i] = 0.f;
  for (int ci0 = 0; ci0 < CI; ci0 += 16) {
    for (int i = tid; i < 16*68; i += 256) {
      int cl = i / 68, tt = i - cl*68;
      int tg = t0 + tt - 2;
      float v = 0.f;
      if (tg >= 0 && tg < 500) {
        if (flags & 1) v = in[((long)b*500 + tg)*80 + (ci0 + cl)];
        else           v = in[((long)b*CI + ci0 + cl)*500 + tg];
      }
      xs[cl][tt] = v;
    }
    __syncthreads();
    for (int cl = 0; cl < 16; ++cl) {
#pragma unroll
      for (int k = 0; k < 5; ++k) {
        const float* wr = wT + ((long)((ci0 + cl)*5 + k))*CO + co0;  // wave-uniform
        float xv = xs[cl][tl + k];
#pragma unroll
        for (int i = 0; i < 16; ++i) acc[i] = fmaf(xv, wr[i], acc[i]);
      }
    }
    __syncthreads();
  }
  int tg = t0 + tl;
  if (tg < 500) {
    const float RS = 0.99999500003749969f;  // 1/sqrt(1+1e-5)  (BN eval)
#pragma unroll
    for (int i = 0; i < 16; ++i) {
      int co = co0 + i;
      if (co < CO) {
        float sc = bg[co] * RS;
        float v = fmaf(acc[i], sc, fmaf(pb[co], sc, bbp[co]));
        if (flags & 4) v = ftanh(v);
        if (flags & 2) { long oi = ((long)b*500 + tg)*80 + co; out[oi] = melp[oi] + v; }
        else out[((long)b*CO + co)*500 + tg] = v;
      }
    }
  }
}

// ---------------- launch ----------------
extern "C" void kernel_launch(void* const* d_in, const int* in_sizes, int n_in,
                              void* d_out, int out_size, void* d_ws, size_t ws_size,
                              hipStream_t stream)
{
  (void)in_sizes; (void)n_in; (void)out_size; (void)ws_size;
  const float* enc     = (const float*)d_in[0];
  const float* mel_tgt = (const float*)d_in[1];
  // p1w=2 p1b=3 p2w=4 p2b=5
  const float* p1w = (const float*)d_in[2];
  const float* p1b = (const float*)d_in[3];
  const float* p2w = (const float*)d_in[4];
  const float* p2b = (const float*)d_in[5];
  const float* wih0 = (const float*)d_in[6];
  const float* whh0 = (const float*)d_in[7];
  const float* bih0 = (const float*)d_in[8];
  const float* bhh0 = (const float*)d_in[9];
  const float* wih1 = (const float*)d_in[10];
  const float* whh1 = (const float*)d_in[11];
  const float* bih1 = (const float*)d_in[12];
  const float* bhh1 = (const float*)d_in[13];
  const float* aq   = (const float*)d_in[14];
  const float* am   = (const float*)d_in[15];
  const float* al   = (const float*)d_in[16];
  const float* alcw = (const float*)d_in[17];
  const float* alcb = (const float*)d_in[18];
  const float* ae   = (const float*)d_in[19];
  const float* ab   = (const float*)d_in[20];
  const float* mw   = (const float*)d_in[21];
  const float* mb   = (const float*)d_in[22];
  const float* sw   = (const float*)d_in[23];
  const float* sb   = (const float*)d_in[24];
  const float* pw0 = (const float*)d_in[25];
  const float* pb0 = (const float*)d_in[26];
  const float* bg0 = (const float*)d_in[27];
  const float* bb0 = (const float*)d_in[28];
  const float* pw1 = (const float*)d_in[29];
  const float* pb1 = (const float*)d_in[30];
  const float* bg1 = (const float*)d_in[31];
  const float* bb1 = (const float*)d_in[32];
  const float* pw2 = (const float*)d_in[33];
  const float* pb2 = (const float*)d_in[34];
  const float* bg2 = (const float*)d_in[35];
  const float* bb2 = (const float*)d_in[36];
  const float* pw3 = (const float*)d_in[37];
  const float* pb3 = (const float*)d_in[38];
  const float* bg3 = (const float*)d_in[39];
  const float* bb3 = (const float*)d_in[40];
  const float* pw4 = (const float*)d_in[41];
  const float* pb4 = (const float*)d_in[42];
  const float* bg4 = (const float*)d_in[43];
  const float* bb4 = (const float*)d_in[44];

  float* ws = (float*)d_ws;
  float* dout = (float*)d_out;

  // prolog
  k_prep<<<dim3(2048), 256, 0, stream>>>(bih0, bhh0, bih1, bhh1, al, alcw, alcb, ab,
                                         am, p1w, p2w, mw, aq, pw0, pw1, pw2, pw3, pw4, ws);
  k_prenet<<<dim3(500), 256, 0, stream>>>(mel_tgt, p1b, p2b, ws);
  k_mem<<<dim3(2048), 256, 0, stream>>>(enc, ws);

  // 500 sequential decode steps
  for (int t = 0; t < 500; ++t) {
    int p = t & 1;
    k_energy<<<dim3(8, 64), 256, 0, stream>>>(ae, dout, ws, t);
    k_softmax_ctx<<<dim3(4, 64), 256, 0, stream>>>(enc, dout, ws, t);
    k_gates_cell<<<dim3(256), 256, 0, stream>>>(wih0, whh0, ws + OFF_GB0, ws, 0, t, p);
    k_gates_cell<<<dim3(256), 256, 0, stream>>>(wih1, whh1, ws + OFF_GB1, ws, 1, t, p);
    k_melstop_q<<<dim3(64), 256, 0, stream>>>(mb, sw, sb, dout, ws, t, p);
  }

  // postnet
  k_conv<<<dim3(8, 8, 64), 256, 0, stream>>>(dout + DO_MEL, ws + OFF_PB0, ws + OFF_PWT0,
                                             pb0, bg0, bb0, nullptr, 80, 512, 1 | 4);
  k_conv<<<dim3(8, 8, 64), 256, 0, stream>>>(ws + OFF_PB0, ws + OFF_PB1, ws + OFF_PWT1,
                                             pb1, bg1, bb1, nullptr, 512, 512, 4);
  k_conv<<<dim3(8, 8, 64), 256, 0, stream>>>(ws + OFF_PB1, ws + OFF_PB0, ws + OFF_PWT2,
                                             pb2, bg2, bb2, nullptr, 512, 512, 4);
  k_conv<<<dim3(8, 8, 64), 256, 0, stream>>>(ws + OFF_PB0, ws + OFF_PB1, ws + OFF_PWT3,
                                             pb3, bg3, bb3, nullptr, 512, 512, 4);
  k_conv<<<dim3(8, 2, 64), 256, 0, stream>>>(ws + OFF_PB1, dout, ws + OFF_PWT4,
                                             pb4, bg4, bb4, dout + DO_MEL, 512, 80, 2);
}